// Round 11
// baseline (687.000 us; speedup 1.0000x reference)
//
#include <hip/hip_runtime.h>
#include <hip/hip_bf16.h>

typedef unsigned short ushort_t;
typedef short short8 __attribute__((ext_vector_type(8)));
typedef short short4v __attribute__((ext_vector_type(4)));
typedef float floatx4 __attribute__((ext_vector_type(4)));

#define FEAT 128
#define HF   512
#define NRBF 50
#define NNODE 10000
#define NEDGE 250000
#define NCHUNK 3907   // ceil(NEDGE/64)

__device__ __forceinline__ float b2f(unsigned int b){
    unsigned int u = (b & 0xffffu) << 16;
    float f; __builtin_memcpy(&f, &u, 4); return f;
}
__device__ __forceinline__ unsigned short f2b(float f){
    __hip_bfloat16 h = __float2bfloat16(f);
    unsigned short u; __builtin_memcpy(&u, &h, 2); return u;
}
__device__ __forceinline__ float silu_f(float x){ return x / (1.f + __expf(-x)); }

// fp32 inputs iff low 16 bits of ln_gamma[0] are zero (R4/R7: fp32 confirmed on HW)
__device__ __forceinline__ bool is_fp32(const void* lng){
    return ((((const unsigned int*)lng)[0]) & 0xffffu) == 0u;
}
__device__ __forceinline__ float ld_f(const void* p, long idx, bool fp32){
    return fp32 ? ((const float*)p)[idx] : b2f(((const ushort_t*)p)[idx]);
}
__device__ __forceinline__ ushort_t ld_bf(const void* p, long idx, bool fp32){
    return fp32 ? f2b(((const float*)p)[idx]) : ((const ushort_t*)p)[idx];
}

// ---------------- sentinel (ws too small; should never fire) --------------------------
__global__ __launch_bounds__(256) void k_sentinel(float* __restrict__ out){
    int x = blockIdx.x*256 + threadIdx.x;
    if (x < NNODE*FEAT*4) out[x] = 1.0f;
}

// ------- fused: normalize nbrs -> int32 + count(dst) + vjb bf16 copy (R20) ------------
__global__ __launch_bounds__(256) void k_nbrs(const unsigned int* __restrict__ raw,
                                              int* __restrict__ out, int* __restrict__ cnt,
                                              const void* __restrict__ v_j,
                                              const void* __restrict__ lng,
                                              ushort_t* __restrict__ vjb){
    int x = blockIdx.x*256 + threadIdx.x;
    const bool fp32 = is_fp32(lng);
    // vjb copy: grid-stride over NNODE*FEAT*3 = 3,840,000 (stride = grid span 500224)
    for (long y = x; y < (long)NNODE*FEAT*3; y += 500224)
        vjb[y] = ld_bf(v_j, y, fp32);
    if (x >= 2*NEDGE) return;
    unsigned int m = raw[1]|raw[3]|raw[5]|raw[7]|raw[9]|raw[11]|raw[13]|raw[15];
    int v = (m == 0u) ? (int)raw[2*x] : (int)raw[x];
    v = ((unsigned)v < (unsigned)NNODE) ? v : 0;
    out[x] = v;
    if (!(x & 1)) atomicAdd(&cnt[v], 1);     // even x = destination i of edge x/2
}

// ---------------- counting sort scan/place (validated R9/R10) -------------------------
__global__ __launch_bounds__(256) void k_scan(const int* __restrict__ cnt, int* __restrict__ cursor){
    __shared__ int part[256];
    __shared__ int base[256];
    const int t = threadIdx.x;
    const int start = t*40;                 // 256*40 = 10240 >= 10000
    int s = 0;
    for (int u=0; u<40; u++){ int idx = start+u; if (idx < NNODE) s += cnt[idx]; }
    part[t] = s;
    __syncthreads();
    if (t == 0){
        int run = 0;
        for (int u=0; u<256; u++){ base[u] = run; run += part[u]; }
    }
    __syncthreads();
    int run = base[t];
    for (int u=0; u<40; u++){
        int idx = start+u;
        if (idx < NNODE){ cursor[idx] = run; run += cnt[idx]; }
    }
}
__global__ __launch_bounds__(256) void k_place(const int* __restrict__ nb32,
                                               int* __restrict__ cursor, int* __restrict__ perm){
    int x = blockIdx.x*256 + threadIdx.x;
    if (x >= NEDGE) return;
    int i = nb32[2*x];
    int pos = atomicAdd(&cursor[i], 1);
    perm[pos] = x;
}

// ------- weight transposes + (block 1792) ln/bias canonicalization (R20 fused) --------
// WqT/WkT/WvT: [512][128]; WdkT/WdvT: [512][64] (k zero-padded 50..63); WdT: [384][512]
// cb (ushort): ln_g@0(128) ln_b@128(128) bq@256 bk@768 bv@1280 bdk@1792 bdv@2304 bd@2816(384)
__global__ __launch_bounds__(256) void k_prep(
    const void* __restrict__ Wq, const void* __restrict__ Wk, const void* __restrict__ Wv,
    const void* __restrict__ Wdk, const void* __restrict__ Wdv, const void* __restrict__ Wd,
    const void* __restrict__ lng, const void* __restrict__ ln_b,
    const void* __restrict__ bq, const void* __restrict__ bk, const void* __restrict__ bv,
    const void* __restrict__ bdk, const void* __restrict__ bdv, const void* __restrict__ bd,
    ushort_t* __restrict__ WqT, ushort_t* __restrict__ WkT, ushort_t* __restrict__ WvT,
    ushort_t* __restrict__ WdkT, ushort_t* __restrict__ WdvT, ushort_t* __restrict__ WdT,
    ushort_t* __restrict__ cb)
{
    const bool fp32 = is_fp32(lng);
    if (blockIdx.x == 1792){
        const int t = threadIdx.x;
        const void* srcs[8] = {lng, ln_b, bq, bk, bv, bdk, bdv, bd};
        const int offs[9] = {0,128,256,768,1280,1792,2304,2816,3200};
        for (int s=0; s<8; s++){
            int c2 = offs[s+1]-offs[s];
            for (int x=t; x<c2; x+=256) cb[offs[s]+x] = ld_bf(srcs[s], x, fp32);
        }
        return;
    }
    int idx = blockIdx.x*256 + threadIdx.x;
    if (idx < 3*65536){
        int mat = idx >> 16; int o = idx & 65535;
        int c = o >> 7, r = o & 127;
        const void* src = (mat==0)?Wq:((mat==1)?Wk:Wv);
        ushort_t* dst = (mat==0)?WqT:((mat==1)?WkT:WvT);
        dst[o] = ld_bf(src, r*HF + c, fp32);
    } else if (idx < 3*65536 + 2*32768){
        int o2 = idx - 3*65536; int mat = o2 >> 15; int o = o2 & 32767;
        int c = o >> 6, kk = o & 63;
        const void* src = mat ? Wdv : Wdk;
        ushort_t* dst = mat ? WdvT : WdkT;
        dst[o] = (kk < NRBF) ? ld_bf(src, kk*HF + c, fp32) : (ushort_t)0;
    } else {
        int o = idx - (3*65536 + 2*32768);
        int c = o >> 9, kk = o & 511;
        WdT[o] = ld_bf(Wd, kk*384 + c, fp32);
    }
}

// ---------------- K1: LayerNorm + QKV projections (MFMA, 32 nodes/block) --------------
// R20: R16's weight-fragment sharing applied to k_qkv2: two 16-node subtiles per block,
//      each Wq/Wk/Wv B-fragment loaded ONCE and fed to TWO MFMAs -> weight L2 requests
//      halved (240MB -> 120MB). 313 blocks.
__global__ __launch_bounds__(256) void k_qkv2(
    const void* __restrict__ s_j, const void* __restrict__ lng, const ushort_t* __restrict__ cb,
    const ushort_t* __restrict__ WqT, const ushort_t* __restrict__ WkT, const ushort_t* __restrict__ WvT,
    ushort_t* __restrict__ q, ushort_t* __restrict__ k, ushort_t* __restrict__ v)
{
    __shared__ __align__(16) ushort_t xlds[2][16][136];   // row stride 272B = 17*16
    const int t = threadIdx.x;
    const int n = t >> 4, g = t & 15;
    const bool fp32 = is_fp32(lng);
    const long base = (long)blockIdx.x*32;

    #pragma unroll
    for (int s=0; s<2; s++){
        long node = base + s*16 + n;
        if (node >= NNODE) node = NNODE-1;       // clamp (outputs of clamped rows unwritten)
        float xs[8];
        if (fp32){
            const float* sf = (const float*)s_j + node*FEAT + g*8;
            #pragma unroll
            for (int i=0;i<8;i++) xs[i] = sf[i];
        } else {
            short8 sv = *reinterpret_cast<const short8*>((const ushort_t*)s_j + node*FEAT + g*8);
            #pragma unroll
            for (int i=0;i<8;i++) xs[i] = b2f((unsigned short)sv[i]);
        }
        float sum = 0.f, ss = 0.f;
        #pragma unroll
        for (int i=0;i<8;i++){ sum += xs[i]; ss += xs[i]*xs[i]; }
        #pragma unroll
        for (int off=8; off; off>>=1){ sum += __shfl_xor(sum, off, 16); ss += __shfl_xor(ss, off, 16); }
        float mu = sum * (1.f/FEAT);
        float var = ss * (1.f/FEAT) - mu*mu;     // population var (jnp.var)
        float sc = rsqrtf(var + 1e-5f);
        short8 gv  = *reinterpret_cast<const short8*>(cb + g*8);
        short8 bv2 = *reinterpret_cast<const short8*>(cb + 128 + g*8);
        short8 xv;
        #pragma unroll
        for (int i=0;i<8;i++){
            float val = (xs[i]-mu)*sc*b2f((unsigned short)gv[i]) + b2f((unsigned short)bv2[i]);
            xv[i] = (short)f2b(val);
        }
        *reinterpret_cast<short8*>(&xlds[s][n][g*8]) = xv;
    }
    __syncthreads();

    const int lane = t & 63, w = t >> 6;
    const int col = lane & 15, quad = lane >> 4;
    short8 a0[4], a1[4];
    #pragma unroll
    for (int ks=0; ks<4; ks++){
        a0[ks] = *reinterpret_cast<const short8*>(&xlds[0][col][ks*32 + quad*8]);
        a1[ks] = *reinterpret_cast<const short8*>(&xlds[1][col][ks*32 + quad*8]);
    }

    for (int ii=0; ii<24; ii++){
        int nt = w + ii*4;
        int mat = nt >> 5, o0 = (nt & 31) << 4;
        const ushort_t* WT  = (mat==0)?WqT:((mat==1)?WkT:WvT);
        const ushort_t* bia = cb + 256 + mat*512;
        ushort_t* outp      = (mat==0)?q:((mat==1)?k:v);
        floatx4 ac0 = {0.f,0.f,0.f,0.f};
        floatx4 ac1 = {0.f,0.f,0.f,0.f};
        #pragma unroll
        for (int ks=0; ks<4; ks++){
            short8 b = *reinterpret_cast<const short8*>(WT + (o0+col)*FEAT + ks*32 + quad*8);
            ac0 = __builtin_amdgcn_mfma_f32_16x16x32_bf16(a0[ks], b, ac0, 0, 0, 0);
            ac1 = __builtin_amdgcn_mfma_f32_16x16x32_bf16(a1[ks], b, ac1, 0, 0, 0);
        }
        float bc = b2f(bia[o0+col]);
        #pragma unroll
        for (int reg=0; reg<4; reg++){
            int row = quad*4 + reg;          // C/D: row=quad*4+reg, col=lane&15
            long n0 = base + row;            // base <= 9984 -> n0 <= 9999, always valid
            outp[n0*HF + o0 + col] = f2b(ac0[reg] + bc);
            long n1 = base + 16 + row;
            if (n1 < NNODE) outp[n1*HF + o0 + col] = f2b(ac1[reg] + bc);
        }
    }
}

// ---------------- K2: fused edge kernel (MFMA), 64 sorted edges/block -----------------
// R21: R18/R20 structure with ONE change: Stage-A thread remap eA=t&15, g=t>>4
//      (was eA=t>>4, g=t&15). Fixes the P3/P4 8-way LDS bank conflict: 16 consecutive
//      lanes now read 16 DIFFERENT dkv rows at the same column (bank group
//      4*eA+16*sub covers all 32 banks per 8-lane service group) instead of one row
//      at stride 64B (banks {0-3}/{16-19} alternating). attn reduction becomes
//      shfl_xor(16)+shfl_xor(32): partials for (edge,head) live at lanes
//      {eA, eA+16, eA+32, eA+48} of wave h (h = wave, sub = lane>>4). All other
//      phases byte-identical. [R17/R19: >=2 independent blocks/CU mandatory.]
struct __align__(16) EdgeSmem {
    int   i[64];
    int   jv[64];
    float unit[64][3];
    ushort_t rbf[4][16][72];            // [sub][edge][rbf] row stride 144B
    union {
        ushort_t dkv[4][16][520];       // [sub][edge][feat]: dk (P2a-P3), then dv/msg
        float    outb[32*385];          // per-epilogue-pass overlay (dkv dead after P5)
    };
};

__global__ __launch_bounds__(256, 2) void k_edge(
    const void* __restrict__ r_ij, const void* __restrict__ lng,
    const int* __restrict__ nbrs32, const int* __restrict__ perm,
    const ushort_t* __restrict__ q, const ushort_t* __restrict__ k, const ushort_t* __restrict__ v,
    const ushort_t* __restrict__ vjb,
    const ushort_t* __restrict__ WdkT, const ushort_t* __restrict__ WdvT,
    const ushort_t* __restrict__ cb,
    const ushort_t* __restrict__ WdT,
    float* __restrict__ acc_s, float* __restrict__ acc_v)
{
    __shared__ EdgeSmem sm;
    const int t = threadIdx.x;
    // XCD-aware swizzle over 3912 = 8*489 blocks; chunk = sorted-edge tile of 64
    const long chunk = (long)(blockIdx.x & 7) * 489 + (blockIdx.x >> 3);
    if (chunk >= NCHUNK) return;
    const long e0 = chunk * 64;
    const int nvalid = (NEDGE - e0 < 64) ? (int)(NEDGE - e0) : 64;
    const bool fp32 = is_fp32(lng);
    const int lane = t & 63, w = t >> 6;
    const int col = lane & 15, quad = lane >> 4;
    const int eA = t & 15, g = t >> 4;      // R21 remap (was eA=t>>4, g=t&15)
    const int h = g >> 2, sub = g & 3;      // within a wave: h = wave idx, sub = lane>>4

    short8 qf[4][4], kf[4][4];
    int jA_s[4];

    // ---- Stage A: 4 subtiles; per thread (eA, g); edge = e0 + s*16 + eA ----
    #pragma unroll
    for (int s=0; s<4; s++){
        const long eidx = e0 + s*16 + eA;
        const long ep = perm[(eidx < NEDGE) ? eidx : (NEDGE-1)];
        const int iA = nbrs32[2*ep];
        const int jA = nbrs32[2*ep+1];
        jA_s[s] = jA;
        float rx = ld_f(r_ij, ep*3+0, fp32);
        float ry = ld_f(r_ij, ep*3+1, fp32);
        float rz = ld_f(r_ij, ep*3+2, fp32);
        float d = sqrtf(rx*rx + ry*ry + rz*rz + 3e-15f);
        float inv = 1.f/d;
        if (g == 0){
            sm.i[s*16+eA] = iA; sm.jv[s*16+eA] = jA;
            sm.unit[s*16+eA][0] = rx*inv; sm.unit[s*16+eA][1] = ry*inv; sm.unit[s*16+eA][2] = rz*inv;
        }
        const float WIDTH = 5.f/49.f;
        const float GAMMA = 0.5f/(WIDTH*WIDTH);
        short4v rv;
        #pragma unroll
        for (int u=0; u<4; u++){
            int m = g*4 + u;
            float val = 0.f;
            if (m < NRBF){ float dm = d - (float)m*WIDTH; val = __expf(-GAMMA*dm*dm); }
            rv[u] = (short)f2b(val);
        }
        *reinterpret_cast<short4v*>(&sm.rbf[s][eA][g*4]) = rv;
        const ushort_t* qp = q + (long)iA*HF + h*128 + sub*32;
        const ushort_t* kp = k + (long)jA*HF + h*128 + sub*32;
        #pragma unroll
        for (int r=0; r<4; r++){
            qf[s][r] = *reinterpret_cast<const short8*>(qp + r*8);
            kf[s][r] = *reinterpret_cast<const short8*>(kp + r*8);
        }
    }
    __syncthreads();

    // ---- P2a: dk = silu(rbf @ Wdk + bdk); each B fragment feeds 4 subtiles ----
    {
        for (int ii=0; ii<8; ii++){
            int nt = w + ii*4;               // 0..31
            int o0 = nt << 4;
            short8 b0 = *reinterpret_cast<const short8*>(WdkT + (o0+col)*64 + quad*8);
            short8 b1 = *reinterpret_cast<const short8*>(WdkT + (o0+col)*64 + 32 + quad*8);
            float bc = b2f(cb[1792 + o0 + col]);
            #pragma unroll
            for (int s=0; s<4; s++){
                short8 a0 = *reinterpret_cast<const short8*>(&sm.rbf[s][col][quad*8]);
                short8 a1 = *reinterpret_cast<const short8*>(&sm.rbf[s][col][32 + quad*8]);
                floatx4 ac = {0.f,0.f,0.f,0.f};
                ac = __builtin_amdgcn_mfma_f32_16x16x32_bf16(a0, b0, ac, 0, 0, 0);
                ac = __builtin_amdgcn_mfma_f32_16x16x32_bf16(a1, b1, ac, 0, 0, 0);
                #pragma unroll
                for (int reg=0; reg<4; reg++){
                    int row = quad*4 + reg;
                    sm.dkv[s][row][o0+col] = f2b(silu_f(ac[reg] + bc));
                }
            }
        }
    }
    __syncthreads();

    // ---- P3: attn -> registers at[4]; issue v prefetch (consumed in P4) ----
    float at[4];
    short8 vf[4][4];
    {
        #pragma unroll
        for (int s=0; s<4; s++){
            const ushort_t* vp = v + (long)jA_s[s]*HF + g*32;
            #pragma unroll
            for (int r=0; r<4; r++) vf[s][r] = *reinterpret_cast<const short8*>(vp + r*8);
        }
        #pragma unroll
        for (int s=0; s<4; s++){
            const ushort_t* dkp = &sm.dkv[s][eA][h*128 + sub*32];
            float p = 0.f;
            #pragma unroll
            for (int r=0; r<4; r++){
                short8 d8 = *reinterpret_cast<const short8*>(dkp + r*8);
                #pragma unroll
                for (int u=0; u<8; u++)
                    p += b2f((unsigned short)qf[s][r][u]) * b2f((unsigned short)kf[s][r][u]) * b2f((unsigned short)d8[u]);
            }
            p += __shfl_xor(p, 16);          // sum over sub (lane bits 4,5)
            p += __shfl_xor(p, 32);
            at[s] = silu_f(p);               // head g>>2 = head of features g*32..+32
        }
    }
    __syncthreads();          // all dk reads done -> dv may overwrite the buffer

    // ---- P2b: dv = silu(rbf @ Wdv + bdv) into the SAME buffer ----
    {
        for (int ii=0; ii<8; ii++){
            int nt = w + ii*4;
            int o0 = nt << 4;
            short8 b0 = *reinterpret_cast<const short8*>(WdvT + (o0+col)*64 + quad*8);
            short8 b1 = *reinterpret_cast<const short8*>(WdvT + (o0+col)*64 + 32 + quad*8);
            float bc = b2f(cb[2304 + o0 + col]);
            #pragma unroll
            for (int s=0; s<4; s++){
                short8 a0 = *reinterpret_cast<const short8*>(&sm.rbf[s][col][quad*8]);
                short8 a1 = *reinterpret_cast<const short8*>(&sm.rbf[s][col][32 + quad*8]);
                floatx4 ac = {0.f,0.f,0.f,0.f};
                ac = __builtin_amdgcn_mfma_f32_16x16x32_bf16(a0, b0, ac, 0, 0, 0);
                ac = __builtin_amdgcn_mfma_f32_16x16x32_bf16(a1, b1, ac, 0, 0, 0);
                #pragma unroll
                for (int reg=0; reg<4; reg++){
                    int row = quad*4 + reg;
                    sm.dkv[s][row][o0+col] = f2b(silu_f(ac[reg] + bc));
                }
            }
        }
    }
    __syncthreads();

    // ---- P4: msg in place over dv: dkv[s][eA][g*32..+32] *= vf[s]*at[s] ----
    #pragma unroll
    for (int s=0; s<4; s++){
        ushort_t* dvp = &sm.dkv[s][eA][g*32];
        #pragma unroll
        for (int r=0; r<4; r++){
            short8 d8 = *reinterpret_cast<const short8*>(dvp + r*8);
            short8 o8;
            #pragma unroll
            for (int u=0; u<8; u++)
                o8[u] = (short)f2b(b2f((unsigned short)vf[s][r][u]) * b2f((unsigned short)d8[u]) * at[s]);
            *reinterpret_cast<short8*>(dvp + r*8) = o8;
        }
    }
    __syncthreads();

    // ---- P5: out = msg(64x512) @ Wd(512x384) + bd; each B fragment feeds 4 MFMAs ----
    floatx4 acc[4][6];
    {
        #pragma unroll
        for (int s=0; s<4; s++)
            #pragma unroll
            for (int ii=0; ii<6; ii++) acc[s][ii] = (floatx4){0.f,0.f,0.f,0.f};
        for (int ks=0; ks<16; ks++){
            short8 a0 = *reinterpret_cast<const short8*>(&sm.dkv[0][col][ks*32 + quad*8]);
            short8 a1 = *reinterpret_cast<const short8*>(&sm.dkv[1][col][ks*32 + quad*8]);
            short8 a2 = *reinterpret_cast<const short8*>(&sm.dkv[2][col][ks*32 + quad*8]);
            short8 a3 = *reinterpret_cast<const short8*>(&sm.dkv[3][col][ks*32 + quad*8]);
            #pragma unroll
            for (int ii=0; ii<6; ii++){
                int o0 = (w + ii*4) << 4;
                short8 b = *reinterpret_cast<const short8*>(WdT + (o0+col)*HF + ks*32 + quad*8);
                acc[0][ii] = __builtin_amdgcn_mfma_f32_16x16x32_bf16(a0, b, acc[0][ii], 0, 0, 0);
                acc[1][ii] = __builtin_amdgcn_mfma_f32_16x16x32_bf16(a1, b, acc[1][ii], 0, 0, 0);
                acc[2][ii] = __builtin_amdgcn_mfma_f32_16x16x32_bf16(a2, b, acc[2][ii], 0, 0, 0);
                acc[3][ii] = __builtin_amdgcn_mfma_f32_16x16x32_bf16(a3, b, acc[3][ii], 0, 0, 0);
            }
        }
    }
    __syncthreads();          // all msg reads done -> dkv dead; outb overlay legal

    // ---- Epilogue: two passes of 32 edges; outb overlay + run-aggregated scatter ----
    {
        const int f = t & 127, half = t >> 7;
        int   cur_i = -1;
        float as = 0.f, av0 = 0.f, av1 = 0.f, av2 = 0.f;
        #pragma unroll
        for (int p=0; p<2; p++){
            // write outb for subtiles 2p, 2p+1 (local rows 0..31)
            #pragma unroll
            for (int ii=0; ii<6; ii++){
                int o0 = (w + ii*4) << 4;
                float bc = b2f(cb[2816 + o0 + col]);
                #pragma unroll
                for (int sl=0; sl<2; sl++){
                    int s = 2*p + sl;
                    #pragma unroll
                    for (int reg=0; reg<4; reg++){
                        int lrow = sl*16 + quad*4 + reg;
                        sm.outb[lrow*385 + o0 + col] = acc[s][ii][reg] + bc;
                    }
                }
            }
            __syncthreads();

            // vjb gather for this pass
            float vjx[16][3];
            #pragma unroll
            for (int u=0; u<16; u++){
                int e = p*32 + half*16 + u;
                const ushort_t* vp = vjb + (long)sm.jv[e]*384 + 3*f;
                vjx[u][0] = b2f(vp[0]); vjx[u][1] = b2f(vp[1]); vjx[u][2] = b2f(vp[2]);
            }
            #pragma unroll
            for (int u=0; u<16; u++){
                int el = half*16 + u;
                int e  = p*32 + el;
                if (e < nvalid){
                    int ie = sm.i[e];
                    if (ie != cur_i){                // uniform across the 128-thread half
                        if (cur_i >= 0){
                            atomicAdd(&acc_s[(long)cur_i*FEAT + f], as);
                            float* ap = acc_v + ((long)cur_i*FEAT + f)*3;
                            atomicAdd(ap+0, av0); atomicAdd(ap+1, av1); atomicAdd(ap+2, av2);
                        }
                        cur_i = ie; as = 0.f; av0 = 0.f; av1 = 0.f; av2 = 0.f;
                    }
                    float o0v = sm.outb[el*385 + f];
                    float o1v = sm.outb[el*385 + 128 + f];
                    float o2v = sm.outb[el*385 + 256 + f];
                    as  += o1v;
                    av0 += o2v*sm.unit[e][0] + o0v*vjx[u][0];
                    av1 += o2v*sm.unit[e][1] + o0v*vjx[u][1];
                    av2 += o2v*sm.unit[e][2] + o0v*vjx[u][2];
                }
            }
            __syncthreads();      // pass reads done before next overlay write
        }
        if (cur_i >= 0){
            atomicAdd(&acc_s[(long)cur_i*FEAT + f], as);
            float* ap = acc_v + ((long)cur_i*FEAT + f)*3;
            atomicAdd(ap+0, av0); atomicAdd(ap+1, av1); atomicAdd(ap+2, av2);
        }
    }
}

extern "C" void kernel_launch(void* const* d_in, const int* in_sizes, int n_in,
                              void* d_out, int out_size, void* d_ws, size_t ws_size,
                              hipStream_t stream)
{
    const void* s_j  = d_in[0];
    const void* v_j  = d_in[1];
    const void* r_ij = d_in[2];
    const unsigned int* nbrs_raw = (const unsigned int*)d_in[3];
    const void* ln_g = d_in[4];
    const void* ln_b = d_in[5];
    const void* Wq = d_in[6];   const void* bq  = d_in[7];
    const void* Wk = d_in[8];   const void* bk  = d_in[9];
    const void* Wv = d_in[10];  const void* bv  = d_in[11];
    const void* Wdk= d_in[12];  const void* bdk = d_in[13];
    const void* Wdv= d_in[14];  const void* bdv = d_in[15];
    const void* Wd = d_in[16];  const void* bd  = d_in[17];

    // ws layout (bytes) — same NEED as R8-R10 (proven):
    //   [0,20.48M): scratch pool: q@0 (10.24M) | vjb@10,240,000 (7.68M) | perm@17,920,000 (1M)
    //               cnt@18,920,000 (40K) | curs@18,960,000 (40K)
    //   kk 20,480,000 | vv 30,720,000 | WqT 40,960,000 WkT WvT | WdkT 41,353,216 WdvT
    //   WdT 41,484,288 | nbrs32 41,877,504 | cb 43,877,504 => NEED 43,883,904
    const size_t NEED = 43883904;
    if (ws_size < NEED){
        k_sentinel<<<20000, 256, 0, stream>>>((float*)d_out);
        return;
    }

    char* ws = (char*)d_ws;
    ushort_t* q    = (ushort_t*)(ws);
    ushort_t* vjb  = (ushort_t*)(ws + 10240000);
    int*      perm = (int*)(ws + 17920000);
    int*      cnt  = (int*)(ws + 18920000);
    int*      curs = (int*)(ws + 18960000);
    ushort_t* kk   = (ushort_t*)(ws + 20480000);
    ushort_t* vv   = (ushort_t*)(ws + 30720000);
    ushort_t* WqT  = (ushort_t*)(ws + 40960000);
    ushort_t* WkT  = (ushort_t*)(ws + 41091072);
    ushort_t* WvT  = (ushort_t*)(ws + 41222144);
    ushort_t* WdkT = (ushort_t*)(ws + 41353216);
    ushort_t* WdvT = (ushort_t*)(ws + 41418752);
    ushort_t* WdT  = (ushort_t*)(ws + 41484288);
    int*      nb32 = (int*)(ws + 41877504);
    ushort_t* cb   = (ushort_t*)(ws + 43877504);

    // atomics accumulate directly into fp32 d_out (20.48 MB): acc_s | acc_v
    float* acc_s = (float*)d_out;
    float* acc_v = acc_s + 1280000;

    hipMemsetAsync(d_out, 0, 20480000, stream);
    hipMemsetAsync(cnt, 0, NNODE*sizeof(int), stream);
    k_nbrs <<<1954, 256, 0, stream>>>(nbrs_raw, nb32, cnt, v_j, ln_g, vjb);
    k_scan <<<1, 256, 0, stream>>>(cnt, curs);
    k_place<<<977, 256, 0, stream>>>(nb32, curs, perm);
    k_prep <<<1793, 256, 0, stream>>>(Wq,Wk,Wv,Wdk,Wdv,Wd, ln_g, ln_b,
                                      bq,bk,bv,bdk,bdv,bd,
                                      WqT,WkT,WvT,WdkT,WdvT,WdT, cb);
    k_qkv2 <<<313, 256, 0, stream>>>(s_j, ln_g, cb, WqT, WkT, WvT, q, kk, vv);
    k_edge <<<3912, 256, 0, stream>>>(r_ij, ln_g, nb32, perm, q, kk, vv, vjb,
                                      WdkT, WdvT, cb, WdT,
                                      acc_s, acc_v);
}

// Round 12
// 666.166 us; speedup vs baseline: 1.0313x; 1.0313x over previous
//
#include <hip/hip_runtime.h>
#include <hip/hip_bf16.h>

typedef unsigned short ushort_t;
typedef short short8 __attribute__((ext_vector_type(8)));
typedef short short4v __attribute__((ext_vector_type(4)));
typedef float floatx4 __attribute__((ext_vector_type(4)));

#define FEAT 128
#define HF   512
#define NRBF 50
#define NNODE 10000
#define NEDGE 250000
#define NCHUNK 3907   // ceil(NEDGE/64)

__device__ __forceinline__ float b2f(unsigned int b){
    unsigned int u = (b & 0xffffu) << 16;
    float f; __builtin_memcpy(&f, &u, 4); return f;
}
__device__ __forceinline__ unsigned short f2b(float f){
    __hip_bfloat16 h = __float2bfloat16(f);
    unsigned short u; __builtin_memcpy(&u, &h, 2); return u;
}
__device__ __forceinline__ float silu_f(float x){ return x / (1.f + __expf(-x)); }

// fp32 inputs iff low 16 bits of ln_gamma[0] are zero (R4/R7: fp32 confirmed on HW)
__device__ __forceinline__ bool is_fp32(const void* lng){
    return ((((const unsigned int*)lng)[0]) & 0xffffu) == 0u;
}
__device__ __forceinline__ float ld_f(const void* p, long idx, bool fp32){
    return fp32 ? ((const float*)p)[idx] : b2f(((const ushort_t*)p)[idx]);
}
__device__ __forceinline__ ushort_t ld_bf(const void* p, long idx, bool fp32){
    return fp32 ? f2b(((const float*)p)[idx]) : ((const ushort_t*)p)[idx];
}

// ---------------- sentinel (ws too small; should never fire) --------------------------
__global__ __launch_bounds__(256) void k_sentinel(float* __restrict__ out){
    int x = blockIdx.x*256 + threadIdx.x;
    if (x < NNODE*FEAT*4) out[x] = 1.0f;
}

// ------- fused: normalize nbrs -> int32 + count(dst) + vjb bf16 copy (R20) ------------
__global__ __launch_bounds__(256) void k_nbrs(const unsigned int* __restrict__ raw,
                                              int* __restrict__ out, int* __restrict__ cnt,
                                              const void* __restrict__ v_j,
                                              const void* __restrict__ lng,
                                              ushort_t* __restrict__ vjb){
    int x = blockIdx.x*256 + threadIdx.x;
    const bool fp32 = is_fp32(lng);
    // vjb copy: grid-stride over NNODE*FEAT*3 = 3,840,000 (stride = grid span 500224)
    for (long y = x; y < (long)NNODE*FEAT*3; y += 500224)
        vjb[y] = ld_bf(v_j, y, fp32);
    if (x >= 2*NEDGE) return;
    unsigned int m = raw[1]|raw[3]|raw[5]|raw[7]|raw[9]|raw[11]|raw[13]|raw[15];
    int v = (m == 0u) ? (int)raw[2*x] : (int)raw[x];
    v = ((unsigned)v < (unsigned)NNODE) ? v : 0;
    out[x] = v;
    if (!(x & 1)) atomicAdd(&cnt[v], 1);     // even x = destination i of edge x/2
}

// ---------------- counting sort scan (validated R9/R10) -------------------------------
__global__ __launch_bounds__(256) void k_scan(const int* __restrict__ cnt, int* __restrict__ cursor){
    __shared__ int part[256];
    __shared__ int base[256];
    const int t = threadIdx.x;
    const int start = t*40;                 // 256*40 = 10240 >= 10000
    int s = 0;
    for (int u=0; u<40; u++){ int idx = start+u; if (idx < NNODE) s += cnt[idx]; }
    part[t] = s;
    __syncthreads();
    if (t == 0){
        int run = 0;
        for (int u=0; u<256; u++){ base[u] = run; run += part[u]; }
    }
    __syncthreads();
    int run = base[t];
    for (int u=0; u<40; u++){
        int idx = start+u;
        if (idx < NNODE){ cursor[idx] = run; run += cnt[idx]; }
    }
}

// ------- R22 merged: k_place (blocks 0..976) + k_prep/cb (blocks 977..2769) -----------
// place and prep are mutually independent (place writes perm via cursor atomics; prep
// writes weight transposes + cb) -> one launch removes a stream-serialization boundary
// and overlaps place's atomic latency with prep's streaming copy.
// WqT/WkT/WvT: [512][128]; WdkT/WdvT: [512][64] (k zero-padded 50..63); WdT: [384][512]
// cb (ushort): ln_g@0(128) ln_b@128(128) bq@256 bk@768 bv@1280 bdk@1792 bdv@2304 bd@2816(384)
__global__ __launch_bounds__(256) void k_pp(
    const int* __restrict__ nb32, int* __restrict__ cursor, int* __restrict__ perm,
    const void* __restrict__ Wq, const void* __restrict__ Wk, const void* __restrict__ Wv,
    const void* __restrict__ Wdk, const void* __restrict__ Wdv, const void* __restrict__ Wd,
    const void* __restrict__ lng, const void* __restrict__ ln_b,
    const void* __restrict__ bq, const void* __restrict__ bk, const void* __restrict__ bv,
    const void* __restrict__ bdk, const void* __restrict__ bdv, const void* __restrict__ bd,
    ushort_t* __restrict__ WqT, ushort_t* __restrict__ WkT, ushort_t* __restrict__ WvT,
    ushort_t* __restrict__ WdkT, ushort_t* __restrict__ WdvT, ushort_t* __restrict__ WdT,
    ushort_t* __restrict__ cb)
{
    if (blockIdx.x < 977){
        // ---- place ----
        int x = blockIdx.x*256 + threadIdx.x;
        if (x >= NEDGE) return;
        int i = nb32[2*x];
        int pos = atomicAdd(&cursor[i], 1);
        perm[pos] = x;
        return;
    }
    const bool fp32 = is_fp32(lng);
    const int pb = blockIdx.x - 977;         // 0..1792
    if (pb == 1792){
        const int t = threadIdx.x;
        const void* srcs[8] = {lng, ln_b, bq, bk, bv, bdk, bdv, bd};
        const int offs[9] = {0,128,256,768,1280,1792,2304,2816,3200};
        for (int s=0; s<8; s++){
            int c2 = offs[s+1]-offs[s];
            for (int x=t; x<c2; x+=256) cb[offs[s]+x] = ld_bf(srcs[s], x, fp32);
        }
        return;
    }
    int idx = pb*256 + threadIdx.x;
    if (idx < 3*65536){
        int mat = idx >> 16; int o = idx & 65535;
        int c = o >> 7, r = o & 127;
        const void* src = (mat==0)?Wq:((mat==1)?Wk:Wv);
        ushort_t* dst = (mat==0)?WqT:((mat==1)?WkT:WvT);
        dst[o] = ld_bf(src, r*HF + c, fp32);
    } else if (idx < 3*65536 + 2*32768){
        int o2 = idx - 3*65536; int mat = o2 >> 15; int o = o2 & 32767;
        int c = o >> 6, kk = o & 63;
        const void* src = mat ? Wdv : Wdk;
        ushort_t* dst = mat ? WdvT : WdkT;
        dst[o] = (kk < NRBF) ? ld_bf(src, kk*HF + c, fp32) : (ushort_t)0;
    } else {
        int o = idx - (3*65536 + 2*32768);
        int c = o >> 9, kk = o & 511;
        WdT[o] = ld_bf(Wd, kk*384 + c, fp32);
    }
}

// ---------------- K1: LayerNorm + QKV projections (MFMA, 32 nodes/block) --------------
// R20: R16's weight-fragment sharing applied to k_qkv2: two 16-node subtiles per block,
//      each Wq/Wk/Wv B-fragment loaded ONCE and fed to TWO MFMAs -> weight L2 requests
//      halved (240MB -> 120MB). 313 blocks.
__global__ __launch_bounds__(256) void k_qkv2(
    const void* __restrict__ s_j, const void* __restrict__ lng, const ushort_t* __restrict__ cb,
    const ushort_t* __restrict__ WqT, const ushort_t* __restrict__ WkT, const ushort_t* __restrict__ WvT,
    ushort_t* __restrict__ q, ushort_t* __restrict__ k, ushort_t* __restrict__ v)
{
    __shared__ __align__(16) ushort_t xlds[2][16][136];   // row stride 272B = 17*16
    const int t = threadIdx.x;
    const int n = t >> 4, g = t & 15;
    const bool fp32 = is_fp32(lng);
    const long base = (long)blockIdx.x*32;

    #pragma unroll
    for (int s=0; s<2; s++){
        long node = base + s*16 + n;
        if (node >= NNODE) node = NNODE-1;       // clamp (outputs of clamped rows unwritten)
        float xs[8];
        if (fp32){
            const float* sf = (const float*)s_j + node*FEAT + g*8;
            #pragma unroll
            for (int i=0;i<8;i++) xs[i] = sf[i];
        } else {
            short8 sv = *reinterpret_cast<const short8*>((const ushort_t*)s_j + node*FEAT + g*8);
            #pragma unroll
            for (int i=0;i<8;i++) xs[i] = b2f((unsigned short)sv[i]);
        }
        float sum = 0.f, ss = 0.f;
        #pragma unroll
        for (int i=0;i<8;i++){ sum += xs[i]; ss += xs[i]*xs[i]; }
        #pragma unroll
        for (int off=8; off; off>>=1){ sum += __shfl_xor(sum, off, 16); ss += __shfl_xor(ss, off, 16); }
        float mu = sum * (1.f/FEAT);
        float var = ss * (1.f/FEAT) - mu*mu;     // population var (jnp.var)
        float sc = rsqrtf(var + 1e-5f);
        short8 gv  = *reinterpret_cast<const short8*>(cb + g*8);
        short8 bv2 = *reinterpret_cast<const short8*>(cb + 128 + g*8);
        short8 xv;
        #pragma unroll
        for (int i=0;i<8;i++){
            float val = (xs[i]-mu)*sc*b2f((unsigned short)gv[i]) + b2f((unsigned short)bv2[i]);
            xv[i] = (short)f2b(val);
        }
        *reinterpret_cast<short8*>(&xlds[s][n][g*8]) = xv;
    }
    __syncthreads();

    const int lane = t & 63, w = t >> 6;
    const int col = lane & 15, quad = lane >> 4;
    short8 a0[4], a1[4];
    #pragma unroll
    for (int ks=0; ks<4; ks++){
        a0[ks] = *reinterpret_cast<const short8*>(&xlds[0][col][ks*32 + quad*8]);
        a1[ks] = *reinterpret_cast<const short8*>(&xlds[1][col][ks*32 + quad*8]);
    }

    for (int ii=0; ii<24; ii++){
        int nt = w + ii*4;
        int mat = nt >> 5, o0 = (nt & 31) << 4;
        const ushort_t* WT  = (mat==0)?WqT:((mat==1)?WkT:WvT);
        const ushort_t* bia = cb + 256 + mat*512;
        ushort_t* outp      = (mat==0)?q:((mat==1)?k:v);
        floatx4 ac0 = {0.f,0.f,0.f,0.f};
        floatx4 ac1 = {0.f,0.f,0.f,0.f};
        #pragma unroll
        for (int ks=0; ks<4; ks++){
            short8 b = *reinterpret_cast<const short8*>(WT + (o0+col)*FEAT + ks*32 + quad*8);
            ac0 = __builtin_amdgcn_mfma_f32_16x16x32_bf16(a0[ks], b, ac0, 0, 0, 0);
            ac1 = __builtin_amdgcn_mfma_f32_16x16x32_bf16(a1[ks], b, ac1, 0, 0, 0);
        }
        float bc = b2f(bia[o0+col]);
        #pragma unroll
        for (int reg=0; reg<4; reg++){
            int row = quad*4 + reg;          // C/D: row=quad*4+reg, col=lane&15
            long n0 = base + row;            // base <= 9984 -> n0 <= 9999, always valid
            outp[n0*HF + o0 + col] = f2b(ac0[reg] + bc);
            long n1 = base + 16 + row;
            if (n1 < NNODE) outp[n1*HF + o0 + col] = f2b(ac1[reg] + bc);
        }
    }
}

// ---------------- K2: fused edge kernel (MFMA), 64 sorted edges/block -----------------
// R20 EXACT (measured best: 507us; protected). R21's bank-conflict remap dropped the
// conflict counter 26% with NO time gain -> conflicts off the critical path; reverted.
// 4-subtile weight amortization at 2 independent blocks/CU; ONE dk/dv buffer
// time-shared via P2a(dk) -> attn->regs at[4] -> P2b(dv) -> P4(msg). LDS 77.3KB.
// Epilogue: two 32-edge outb passes overlaying dead dkv.
// [R17/R19: >=2 independent blocks/CU mandatory; R21: LDS conflicts not limiting.]
struct __align__(16) EdgeSmem {
    int   i[64];
    int   jv[64];
    float unit[64][3];
    ushort_t rbf[4][16][72];            // [sub][edge][rbf] row stride 144B
    union {
        ushort_t dkv[4][16][520];       // [sub][edge][feat]: dk (P2a-P3), then dv/msg
        float    outb[32*385];          // per-epilogue-pass overlay (dkv dead after P5)
    };
};

__global__ __launch_bounds__(256, 2) void k_edge(
    const void* __restrict__ r_ij, const void* __restrict__ lng,
    const int* __restrict__ nbrs32, const int* __restrict__ perm,
    const ushort_t* __restrict__ q, const ushort_t* __restrict__ k, const ushort_t* __restrict__ v,
    const ushort_t* __restrict__ vjb,
    const ushort_t* __restrict__ WdkT, const ushort_t* __restrict__ WdvT,
    const ushort_t* __restrict__ cb,
    const ushort_t* __restrict__ WdT,
    float* __restrict__ acc_s, float* __restrict__ acc_v)
{
    __shared__ EdgeSmem sm;
    const int t = threadIdx.x;
    // XCD-aware swizzle over 3912 = 8*489 blocks; chunk = sorted-edge tile of 64
    const long chunk = (long)(blockIdx.x & 7) * 489 + (blockIdx.x >> 3);
    if (chunk >= NCHUNK) return;
    const long e0 = chunk * 64;
    const int nvalid = (NEDGE - e0 < 64) ? (int)(NEDGE - e0) : 64;
    const bool fp32 = is_fp32(lng);
    const int lane = t & 63, w = t >> 6;
    const int col = lane & 15, quad = lane >> 4;
    const int eA = t >> 4, g = t & 15;
    const int h = g >> 2, sub = g & 3;

    short8 qf[4][4], kf[4][4];
    int jA_s[4];

    // ---- Stage A: 4 subtiles; per thread (eA, g); edge = e0 + s*16 + eA ----
    #pragma unroll
    for (int s=0; s<4; s++){
        const long eidx = e0 + s*16 + eA;
        const long ep = perm[(eidx < NEDGE) ? eidx : (NEDGE-1)];
        const int iA = nbrs32[2*ep];
        const int jA = nbrs32[2*ep+1];
        jA_s[s] = jA;
        float rx = ld_f(r_ij, ep*3+0, fp32);
        float ry = ld_f(r_ij, ep*3+1, fp32);
        float rz = ld_f(r_ij, ep*3+2, fp32);
        float d = sqrtf(rx*rx + ry*ry + rz*rz + 3e-15f);
        float inv = 1.f/d;
        if (g == 0){
            sm.i[s*16+eA] = iA; sm.jv[s*16+eA] = jA;
            sm.unit[s*16+eA][0] = rx*inv; sm.unit[s*16+eA][1] = ry*inv; sm.unit[s*16+eA][2] = rz*inv;
        }
        const float WIDTH = 5.f/49.f;
        const float GAMMA = 0.5f/(WIDTH*WIDTH);
        short4v rv;
        #pragma unroll
        for (int u=0; u<4; u++){
            int m = g*4 + u;
            float val = 0.f;
            if (m < NRBF){ float dm = d - (float)m*WIDTH; val = __expf(-GAMMA*dm*dm); }
            rv[u] = (short)f2b(val);
        }
        *reinterpret_cast<short4v*>(&sm.rbf[s][eA][g*4]) = rv;
        const ushort_t* qp = q + (long)iA*HF + h*128 + sub*32;
        const ushort_t* kp = k + (long)jA*HF + h*128 + sub*32;
        #pragma unroll
        for (int r=0; r<4; r++){
            qf[s][r] = *reinterpret_cast<const short8*>(qp + r*8);
            kf[s][r] = *reinterpret_cast<const short8*>(kp + r*8);
        }
    }
    __syncthreads();

    // ---- P2a: dk = silu(rbf @ Wdk + bdk); each B fragment feeds 4 subtiles ----
    {
        for (int ii=0; ii<8; ii++){
            int nt = w + ii*4;               // 0..31
            int o0 = nt << 4;
            short8 b0 = *reinterpret_cast<const short8*>(WdkT + (o0+col)*64 + quad*8);
            short8 b1 = *reinterpret_cast<const short8*>(WdkT + (o0+col)*64 + 32 + quad*8);
            float bc = b2f(cb[1792 + o0 + col]);
            #pragma unroll
            for (int s=0; s<4; s++){
                short8 a0 = *reinterpret_cast<const short8*>(&sm.rbf[s][col][quad*8]);
                short8 a1 = *reinterpret_cast<const short8*>(&sm.rbf[s][col][32 + quad*8]);
                floatx4 ac = {0.f,0.f,0.f,0.f};
                ac = __builtin_amdgcn_mfma_f32_16x16x32_bf16(a0, b0, ac, 0, 0, 0);
                ac = __builtin_amdgcn_mfma_f32_16x16x32_bf16(a1, b1, ac, 0, 0, 0);
                #pragma unroll
                for (int reg=0; reg<4; reg++){
                    int row = quad*4 + reg;
                    sm.dkv[s][row][o0+col] = f2b(silu_f(ac[reg] + bc));
                }
            }
        }
    }
    __syncthreads();

    // ---- P3: attn -> registers at[4]; issue v prefetch (consumed in P4) ----
    float at[4];
    short8 vf[4][4];
    {
        #pragma unroll
        for (int s=0; s<4; s++){
            const ushort_t* vp = v + (long)jA_s[s]*HF + g*32;
            #pragma unroll
            for (int r=0; r<4; r++) vf[s][r] = *reinterpret_cast<const short8*>(vp + r*8);
        }
        #pragma unroll
        for (int s=0; s<4; s++){
            const ushort_t* dkp = &sm.dkv[s][eA][h*128 + sub*32];
            float p = 0.f;
            #pragma unroll
            for (int r=0; r<4; r++){
                short8 d8 = *reinterpret_cast<const short8*>(dkp + r*8);
                #pragma unroll
                for (int u=0; u<8; u++)
                    p += b2f((unsigned short)qf[s][r][u]) * b2f((unsigned short)kf[s][r][u]) * b2f((unsigned short)d8[u]);
            }
            p += __shfl_xor(p, 1);
            p += __shfl_xor(p, 2);
            at[s] = silu_f(p);         // head g>>2 = head of features g*32..+32
        }
    }
    __syncthreads();          // all dk reads done -> dv may overwrite the buffer

    // ---- P2b: dv = silu(rbf @ Wdv + bdv) into the SAME buffer ----
    {
        for (int ii=0; ii<8; ii++){
            int nt = w + ii*4;
            int o0 = nt << 4;
            short8 b0 = *reinterpret_cast<const short8*>(WdvT + (o0+col)*64 + quad*8);
            short8 b1 = *reinterpret_cast<const short8*>(WdvT + (o0+col)*64 + 32 + quad*8);
            float bc = b2f(cb[2304 + o0 + col]);
            #pragma unroll
            for (int s=0; s<4; s++){
                short8 a0 = *reinterpret_cast<const short8*>(&sm.rbf[s][col][quad*8]);
                short8 a1 = *reinterpret_cast<const short8*>(&sm.rbf[s][col][32 + quad*8]);
                floatx4 ac = {0.f,0.f,0.f,0.f};
                ac = __builtin_amdgcn_mfma_f32_16x16x32_bf16(a0, b0, ac, 0, 0, 0);
                ac = __builtin_amdgcn_mfma_f32_16x16x32_bf16(a1, b1, ac, 0, 0, 0);
                #pragma unroll
                for (int reg=0; reg<4; reg++){
                    int row = quad*4 + reg;
                    sm.dkv[s][row][o0+col] = f2b(silu_f(ac[reg] + bc));
                }
            }
        }
    }
    __syncthreads();

    // ---- P4: msg in place over dv: dkv[s][eA][g*32..+32] *= vf[s]*at[s] ----
    #pragma unroll
    for (int s=0; s<4; s++){
        ushort_t* dvp = &sm.dkv[s][eA][g*32];
        #pragma unroll
        for (int r=0; r<4; r++){
            short8 d8 = *reinterpret_cast<const short8*>(dvp + r*8);
            short8 o8;
            #pragma unroll
            for (int u=0; u<8; u++)
                o8[u] = (short)f2b(b2f((unsigned short)vf[s][r][u]) * b2f((unsigned short)d8[u]) * at[s]);
            *reinterpret_cast<short8*>(dvp + r*8) = o8;
        }
    }
    __syncthreads();

    // ---- P5: out = msg(64x512) @ Wd(512x384) + bd; each B fragment feeds 4 MFMAs ----
    floatx4 acc[4][6];
    {
        #pragma unroll
        for (int s=0; s<4; s++)
            #pragma unroll
            for (int ii=0; ii<6; ii++) acc[s][ii] = (floatx4){0.f,0.f,0.f,0.f};
        for (int ks=0; ks<16; ks++){
            short8 a0 = *reinterpret_cast<const short8*>(&sm.dkv[0][col][ks*32 + quad*8]);
            short8 a1 = *reinterpret_cast<const short8*>(&sm.dkv[1][col][ks*32 + quad*8]);
            short8 a2 = *reinterpret_cast<const short8*>(&sm.dkv[2][col][ks*32 + quad*8]);
            short8 a3 = *reinterpret_cast<const short8*>(&sm.dkv[3][col][ks*32 + quad*8]);
            #pragma unroll
            for (int ii=0; ii<6; ii++){
                int o0 = (w + ii*4) << 4;
                short8 b = *reinterpret_cast<const short8*>(WdT + (o0+col)*HF + ks*32 + quad*8);
                acc[0][ii] = __builtin_amdgcn_mfma_f32_16x16x32_bf16(a0, b, acc[0][ii], 0, 0, 0);
                acc[1][ii] = __builtin_amdgcn_mfma_f32_16x16x32_bf16(a1, b, acc[1][ii], 0, 0, 0);
                acc[2][ii] = __builtin_amdgcn_mfma_f32_16x16x32_bf16(a2, b, acc[2][ii], 0, 0, 0);
                acc[3][ii] = __builtin_amdgcn_mfma_f32_16x16x32_bf16(a3, b, acc[3][ii], 0, 0, 0);
            }
        }
    }
    __syncthreads();          // all msg reads done -> dkv dead; outb overlay legal

    // ---- Epilogue: two passes of 32 edges; outb overlay + run-aggregated scatter ----
    {
        const int f = t & 127, half = t >> 7;
        int   cur_i = -1;
        float as = 0.f, av0 = 0.f, av1 = 0.f, av2 = 0.f;
        #pragma unroll
        for (int p=0; p<2; p++){
            // write outb for subtiles 2p, 2p+1 (local rows 0..31)
            #pragma unroll
            for (int ii=0; ii<6; ii++){
                int o0 = (w + ii*4) << 4;
                float bc = b2f(cb[2816 + o0 + col]);
                #pragma unroll
                for (int sl=0; sl<2; sl++){
                    int s = 2*p + sl;
                    #pragma unroll
                    for (int reg=0; reg<4; reg++){
                        int lrow = sl*16 + quad*4 + reg;
                        sm.outb[lrow*385 + o0 + col] = acc[s][ii][reg] + bc;
                    }
                }
            }
            __syncthreads();

            // vjb gather for this pass
            float vjx[16][3];
            #pragma unroll
            for (int u=0; u<16; u++){
                int e = p*32 + half*16 + u;
                const ushort_t* vp = vjb + (long)sm.jv[e]*384 + 3*f;
                vjx[u][0] = b2f(vp[0]); vjx[u][1] = b2f(vp[1]); vjx[u][2] = b2f(vp[2]);
            }
            #pragma unroll
            for (int u=0; u<16; u++){
                int el = half*16 + u;
                int e  = p*32 + el;
                if (e < nvalid){
                    int ie = sm.i[e];
                    if (ie != cur_i){                // uniform across the 128-thread half
                        if (cur_i >= 0){
                            atomicAdd(&acc_s[(long)cur_i*FEAT + f], as);
                            float* ap = acc_v + ((long)cur_i*FEAT + f)*3;
                            atomicAdd(ap+0, av0); atomicAdd(ap+1, av1); atomicAdd(ap+2, av2);
                        }
                        cur_i = ie; as = 0.f; av0 = 0.f; av1 = 0.f; av2 = 0.f;
                    }
                    float o0v = sm.outb[el*385 + f];
                    float o1v = sm.outb[el*385 + 128 + f];
                    float o2v = sm.outb[el*385 + 256 + f];
                    as  += o1v;
                    av0 += o2v*sm.unit[e][0] + o0v*vjx[u][0];
                    av1 += o2v*sm.unit[e][1] + o0v*vjx[u][1];
                    av2 += o2v*sm.unit[e][2] + o0v*vjx[u][2];
                }
            }
            __syncthreads();      // pass reads done before next overlay write
        }
        if (cur_i >= 0){
            atomicAdd(&acc_s[(long)cur_i*FEAT + f], as);
            float* ap = acc_v + ((long)cur_i*FEAT + f)*3;
            atomicAdd(ap+0, av0); atomicAdd(ap+1, av1); atomicAdd(ap+2, av2);
        }
    }
}

extern "C" void kernel_launch(void* const* d_in, const int* in_sizes, int n_in,
                              void* d_out, int out_size, void* d_ws, size_t ws_size,
                              hipStream_t stream)
{
    const void* s_j  = d_in[0];
    const void* v_j  = d_in[1];
    const void* r_ij = d_in[2];
    const unsigned int* nbrs_raw = (const unsigned int*)d_in[3];
    const void* ln_g = d_in[4];
    const void* ln_b = d_in[5];
    const void* Wq = d_in[6];   const void* bq  = d_in[7];
    const void* Wk = d_in[8];   const void* bk  = d_in[9];
    const void* Wv = d_in[10];  const void* bv  = d_in[11];
    const void* Wdk= d_in[12];  const void* bdk = d_in[13];
    const void* Wdv= d_in[14];  const void* bdv = d_in[15];
    const void* Wd = d_in[16];  const void* bd  = d_in[17];

    // ws layout (bytes) — same NEED as R8-R10 (proven):
    //   [0,20.48M): scratch pool: q@0 (10.24M) | vjb@10,240,000 (7.68M) | perm@17,920,000 (1M)
    //               cnt@18,920,000 (40K) | curs@18,960,000 (40K)
    //   kk 20,480,000 | vv 30,720,000 | WqT 40,960,000 WkT WvT | WdkT 41,353,216 WdvT
    //   WdT 41,484,288 | nbrs32 41,877,504 | cb 43,877,504 => NEED 43,883,904
    const size_t NEED = 43883904;
    if (ws_size < NEED){
        k_sentinel<<<20000, 256, 0, stream>>>((float*)d_out);
        return;
    }

    char* ws = (char*)d_ws;
    ushort_t* q    = (ushort_t*)(ws);
    ushort_t* vjb  = (ushort_t*)(ws + 10240000);
    int*      perm = (int*)(ws + 17920000);
    int*      cnt  = (int*)(ws + 18920000);
    int*      curs = (int*)(ws + 18960000);
    ushort_t* kk   = (ushort_t*)(ws + 20480000);
    ushort_t* vv   = (ushort_t*)(ws + 30720000);
    ushort_t* WqT  = (ushort_t*)(ws + 40960000);
    ushort_t* WkT  = (ushort_t*)(ws + 41091072);
    ushort_t* WvT  = (ushort_t*)(ws + 41222144);
    ushort_t* WdkT = (ushort_t*)(ws + 41353216);
    ushort_t* WdvT = (ushort_t*)(ws + 41418752);
    ushort_t* WdT  = (ushort_t*)(ws + 41484288);
    int*      nb32 = (int*)(ws + 41877504);
    ushort_t* cb   = (ushort_t*)(ws + 43877504);

    // atomics accumulate directly into fp32 d_out (20.48 MB): acc_s | acc_v
    float* acc_s = (float*)d_out;
    float* acc_v = acc_s + 1280000;

    hipMemsetAsync(d_out, 0, 20480000, stream);
    hipMemsetAsync(cnt, 0, NNODE*sizeof(int), stream);
    k_nbrs <<<1954, 256, 0, stream>>>(nbrs_raw, nb32, cnt, v_j, ln_g, vjb);
    k_scan <<<1, 256, 0, stream>>>(cnt, curs);
    k_pp   <<<2770, 256, 0, stream>>>(nb32, curs, perm,
                                      Wq,Wk,Wv,Wdk,Wdv,Wd, ln_g, ln_b,
                                      bq,bk,bv,bdk,bdv,bd,
                                      WqT,WkT,WvT,WdkT,WdvT,WdT, cb);
    k_qkv2 <<<313, 256, 0, stream>>>(s_j, ln_g, cb, WqT, WkT, WvT, q, kk, vv);
    k_edge <<<3912, 256, 0, stream>>>(r_ij, ln_g, nb32, perm, q, kk, vv, vjb,
                                      WdkT, WdvT, cb, WdT,
                                      acc_s, acc_v);
}